// Round 9
// baseline (1030.740 us; speedup 1.0000x reference)
//
#include <hip/hip_runtime.h>
#include <hip/hip_cooperative_groups.h>
#include <cstdint>
#include <cstddef>
#include <math.h>

namespace cg = cooperative_groups;

#define NEG_SLOPE 0.2f

__device__ __forceinline__ float lrelu(float x) { return x > 0.f ? x : NEG_SLOPE * x; }

// ================= K1: GEMM (blocks < GB) UNION degree-count (blocks >= GB) ======
// xw written slice-major [8][N][16]; a_src/a_dst [N][4].
__global__ __launch_bounds__(256) void k_gemm_count(
    const float* __restrict__ x, const float* __restrict__ W1,
    const float* __restrict__ att_src, const float* __restrict__ att_dst,
    const int* __restrict__ ei, int E, int N, int GB,
    float* __restrict__ xw, float* __restrict__ a_src, float* __restrict__ a_dst,
    int* __restrict__ deg)
{
    __shared__ float As[32 * 68];
    __shared__ float Bs[32 * 132];

    if (blockIdx.x >= GB) {                    // ---- count blocks (overlap with GEMM)
        const int Et = E + N;
        const int stride = (gridDim.x - GB) * 256;
        for (int e = (blockIdx.x - GB) * 256 + threadIdx.x; e < Et; e += stride) {
            int d = (e < E) ? ei[(size_t)E + e] : (e - E);
            atomicAdd(&deg[d], 1);
        }
        return;
    }

    const int tid = threadIdx.x;
    const int tx = tid & 31, ty = tid >> 5;
    const int bm = blockIdx.x * 64;
    float acc[8][4] = {};

    for (int k0 = 0; k0 < 128; k0 += 32) {
        #pragma unroll
        for (int t = tid; t < 512; t += 256) {
            int r = t >> 3, q = t & 7;
            int n = bm + r;
            float4 f = make_float4(0.f, 0.f, 0.f, 0.f);
            if (n < N) f = *(const float4*)(x + (size_t)n * 128 + k0 + 4 * q);
            As[(4*q+0)*68 + r] = f.x; As[(4*q+1)*68 + r] = f.y;
            As[(4*q+2)*68 + r] = f.z; As[(4*q+3)*68 + r] = f.w;
        }
        #pragma unroll
        for (int t = tid; t < 1024; t += 256) {
            int c = t >> 3, q = t & 7;
            float4 f = *(const float4*)(W1 + (size_t)c * 128 + k0 + 4 * q);
            Bs[(4*q+0)*132 + c] = f.x; Bs[(4*q+1)*132 + c] = f.y;
            Bs[(4*q+2)*132 + c] = f.z; Bs[(4*q+3)*132 + c] = f.w;
        }
        __syncthreads();
        #pragma unroll 8
        for (int kk = 0; kk < 32; kk++) {
            float4 a0 = *(const float4*)&As[kk * 68 + ty * 8];
            float4 a1 = *(const float4*)&As[kk * 68 + ty * 8 + 4];
            float4 b4 = *(const float4*)&Bs[kk * 132 + tx * 4];
            float a[8] = {a0.x, a0.y, a0.z, a0.w, a1.x, a1.y, a1.z, a1.w};
            float b[4] = {b4.x, b4.y, b4.z, b4.w};
            #pragma unroll
            for (int i = 0; i < 8; i++)
                #pragma unroll
                for (int j = 0; j < 4; j++) acc[i][j] = fmaf(a[i], b[j], acc[i][j]);
        }
        __syncthreads();
    }

    float asv[4], adv[4];
    #pragma unroll
    for (int j = 0; j < 4; j++) { asv[j] = att_src[tx*4+j]; adv[j] = att_dst[tx*4+j]; }
    const int slice = tx >> 2, cio = (tx & 3) * 4, head = tx >> 3;

    #pragma unroll
    for (int i = 0; i < 8; i++) {
        int n = bm + ty * 8 + i;
        float sv = 0.f, dv = 0.f;
        #pragma unroll
        for (int j = 0; j < 4; j++) {
            sv = fmaf(acc[i][j], asv[j], sv);
            dv = fmaf(acc[i][j], adv[j], dv);
        }
        #pragma unroll
        for (int off = 1; off < 8; off <<= 1) {   // 8 lanes of one head
            sv += __shfl_xor(sv, off);
            dv += __shfl_xor(dv, off);
        }
        if (n < N) {
            *(float4*)&xw[((size_t)slice * N + n) * 16 + cio] =
                make_float4(acc[i][0], acc[i][1], acc[i][2], acc[i][3]);
            if ((tx & 7) == 0) {
                a_src[n * 4 + head] = sv;
                a_dst[n * 4 + head] = dv;
            }
        }
    }
}

// ================= K2: cooperative persistent — scan | scatter+pk | agg | layer2 ==
// launch_bounds(256,4): ample occupancy slack so the cooperative launch cannot be
// rejected (r8's 6/CU-exact NB=1536 was refused and silently did nothing).
__global__ __launch_bounds__(256, 4) void k_fused(
    const float* __restrict__ xw, const float* __restrict__ a_src,
    const float* __restrict__ a_dst, const int* __restrict__ ei, int E, int N,
    int* __restrict__ deg,
    int* __restrict__ row_ptr, int* __restrict__ cursor, int* __restrict__ partial,
    uint2* __restrict__ pk, float* __restrict__ xw2,
    const float* __restrict__ b1, const float* __restrict__ W2,
    const float* __restrict__ att_src2, const float* __restrict__ att_dst2,
    const float* __restrict__ b2, float* __restrict__ out)
{
    cg::grid_group grid = cg::this_grid();
    const int tid = threadIdx.x, b = blockIdx.x, nb = gridDim.x;
    const int wv = tid >> 6, lane = tid & 63;
    const int Et = E + N;
    __shared__ int sw[4];

    // ---- A1: block-local scan of deg (single pass: N <= nb*256); zero xw2
    const int idx = b * 256 + tid;
    int v = (idx < N) ? deg[idx] : 0;
    if (idx < N) xw2[idx] = 0.f;
    int inc = v;
    #pragma unroll
    for (int off = 1; off < 64; off <<= 1) {
        int u = __shfl_up(inc, off);
        if (lane >= off) inc += u;
    }
    if (lane == 63) sw[wv] = inc;
    __syncthreads();
    int woff = 0;
    for (int i = 0; i < wv; i++) woff += sw[i];
    const int excl_in_block = woff + inc - v;
    if (tid == 0) partial[b] = sw[0] + sw[1] + sw[2] + sw[3];
    grid.sync();   // ---- sync 1

    // ---- A2: block 0 scans the nb partials (nb <= 2048 -> seg <= 8)
    if (b == 0) {
        const int seg = (nb + 255) / 256;
        int base = tid * seg;
        int p[8], s = 0;
        for (int i = 0; i < seg; i++) {
            int k = base + i;
            p[i] = (k < nb) ? partial[k] : 0;
            s += p[i];
        }
        int sinc = s;
        #pragma unroll
        for (int off = 1; off < 64; off <<= 1) {
            int u = __shfl_up(sinc, off);
            if (lane >= off) sinc += u;
        }
        if (lane == 63) sw[wv] = sinc;
        __syncthreads();
        int w2 = 0;
        for (int i = 0; i < wv; i++) w2 += sw[i];
        int ex = w2 + sinc - s;
        for (int i = 0; i < seg; i++) {
            int k = base + i;
            if (k < nb) partial[k] = ex;
            ex += p[i];
        }
        if (tid == 0) row_ptr[N] = sw[0] + sw[1] + sw[2] + sw[3];
    }
    grid.sync();   // ---- sync 2

    // ---- A3: write row_ptr / cursor
    if (idx < N) {
        int rp = partial[b] + excl_in_block;
        row_ptr[idx] = rp;
        cursor[idx]  = rp;
    }
    grid.sync();   // ---- sync 3

    // ---- B: scatter + packed unnormalized softmax weights into pk[4][Et]
    for (int e = b * 256 + tid; e < Et; e += nb * 256) {
        int s, d;
        if (e < E) { s = ei[e]; d = ei[(size_t)E + e]; }
        else       { s = d = e - E; }
        int pos = atomicAdd(&cursor[d], 1);
        float4 as4 = ((const float4*)a_src)[s];
        float4 ad4 = ((const float4*)a_dst)[d];
        unsigned us = (unsigned)s;
        pk[(size_t)0 * Et + pos] = make_uint2(us, __float_as_uint(__expf(lrelu(as4.x + ad4.x))));
        pk[(size_t)1 * Et + pos] = make_uint2(us, __float_as_uint(__expf(lrelu(as4.y + ad4.y))));
        pk[(size_t)2 * Et + pos] = make_uint2(us, __float_as_uint(__expf(lrelu(as4.z + ad4.z))));
        pk[(size_t)3 * Et + pos] = make_uint2(us, __float_as_uint(__expf(lrelu(as4.w + ad4.w))));
    }
    grid.sync();   // ---- sync 4

    // ---- C: aggregation. slice = blockIdx&7 (r6-proven L2 pinning), static stride.
    {
        const int slice = b & 7, rank = b >> 3;
        const int nper  = nb >> 3;               // nb is a multiple of 8
        const int head  = slice >> 1;
        const float4* xs4 = (const float4*)(xw + (size_t)slice * N * 16);
        const uint2*  ph  = pk + (size_t)head * Et;
        const int slot = lane >> 2, li = lane & 3;
        const int ng = (N + 3) >> 2;
        for (int g = rank; g < ng; g += nper) {
            int d = g * 4 + wv;
            if (d < N) {
                int beg = row_ptr[d];
                int dg  = row_ptr[d + 1] - beg;
                float4 acc = make_float4(0.f, 0.f, 0.f, 0.f);
                float csum = 0.f;
                #pragma unroll 2
                for (int k = slot; k < dg; k += 16) {
                    uint2 p = ph[beg + k];
                    float c = __uint_as_float(p.y);
                    float4 vv = xs4[(size_t)p.x * 4 + li];
                    acc.x = fmaf(c, vv.x, acc.x);
                    acc.y = fmaf(c, vv.y, acc.y);
                    acc.z = fmaf(c, vv.z, acc.z);
                    acc.w = fmaf(c, vv.w, acc.w);
                    csum += c;
                }
                #pragma unroll
                for (int off = 4; off < 64; off <<= 1) {
                    acc.x += __shfl_xor(acc.x, off);
                    acc.y += __shfl_xor(acc.y, off);
                    acc.z += __shfl_xor(acc.z, off);
                    acc.w += __shfl_xor(acc.w, off);
                    csum  += __shfl_xor(csum, off);
                }
                float4 bb = ((const float4*)b1)[slice * 4 + li];
                float4 ww = ((const float4*)W2)[slice * 4 + li];
                float inv = 1.f / (csum + 1e-16f);
                float t = fmaxf(fmaf(acc.x, inv, bb.x), 0.f) * ww.x
                        + fmaxf(fmaf(acc.y, inv, bb.y), 0.f) * ww.y
                        + fmaxf(fmaf(acc.z, inv, bb.z), 0.f) * ww.z
                        + fmaxf(fmaf(acc.w, inv, bb.w), 0.f) * ww.w;
                t += __shfl_xor(t, 1);
                t += __shfl_xor(t, 2);
                if (lane == 0) atomicAdd(&xw2[d], t);
            }
        }
    }
    grid.sync();   // ---- sync 5

    // ---- D: layer 2 (scalar GAT head), 4 dsts/wave x 16 lanes, persistent
    {
        const float as2 = att_src2[0], ad2 = att_dst2[0], bb2 = b2[0];
        const int sub = lane >> 4, li = lane & 15;
        const int ngrp = (N + 3) >> 2;
        for (int g = b * 4 + wv; g < ngrp; g += nb * 4) {
            int d = g * 4 + sub;
            float l = 0.f, acc = 0.f;
            if (d < N) {
                float adst = xw2[d] * ad2;
                int beg = row_ptr[d], end = row_ptr[d + 1];
                for (int j = beg + li; j < end; j += 16) {
                    int s = (int)pk[j].x;             // plane 0
                    float xv = xw2[s];
                    float pe = __expf(lrelu(fmaf(xv, as2, adst)));
                    l += pe;
                    acc = fmaf(pe, xv, acc);
                }
            }
            #pragma unroll
            for (int off = 1; off < 16; off <<= 1) {
                l   += __shfl_xor(l, off);
                acc += __shfl_xor(acc, off);
            }
            if (d < N && li == 0) out[d] = acc / (l + 1e-16f) + bb2;
        }
    }
}

extern "C" void kernel_launch(void* const* d_in, const int* in_sizes, int n_in,
                              void* d_out, int out_size, void* d_ws, size_t ws_size,
                              hipStream_t stream)
{
    const float* x        = (const float*)d_in[0];
    const int*   ei       = (const int*)d_in[1];
    const float* W1       = (const float*)d_in[2];
    const float* att_src1 = (const float*)d_in[3];
    const float* att_dst1 = (const float*)d_in[4];
    const float* b1       = (const float*)d_in[5];
    const float* W2       = (const float*)d_in[6];
    const float* att_src2 = (const float*)d_in[7];
    const float* att_dst2 = (const float*)d_in[8];
    const float* b2       = (const float*)d_in[9];
    float* out = (float*)d_out;

    const int N  = in_sizes[0] / 128;
    const int E  = in_sizes[1] / 2;
    const int Et = E + N;

    char* p = (char*)d_ws;
    auto alloc = [&](size_t bytes) {
        char* r = p;
        p += (bytes + 255) & ~(size_t)255;
        return (void*)r;
    };
    float* xw      = (float*)alloc((size_t)N * 128 * 4);   // slice-major [8][N][16]
    float* a_src   = (float*)alloc((size_t)N * 4 * 4);
    float* a_dst   = (float*)alloc((size_t)N * 4 * 4);
    float* xw2     = (float*)alloc((size_t)N * 4);
    int*   deg     = (int*)alloc((size_t)N * 4);
    int*   row_ptr = (int*)alloc((size_t)(N + 1) * 4);
    int*   cursor  = (int*)alloc((size_t)N * 4);
    int*   partial = (int*)alloc((size_t)2048 * 4);
    uint2* pk      = (uint2*)alloc((size_t)4 * Et * 8);    // [4][Et] packed {s, e_h}

    hipMemsetAsync(deg, 0, (size_t)N * 4, stream);

    const int GB = (N + 63) / 64;
    k_gemm_count<<<GB + 256, 256, 0, stream>>>(x, W1, att_src1, att_dst1, ei, E, N, GB,
                                               xw, a_src, a_dst, deg);

    // Cooperative grid sized from the runtime's own occupancy answer: can't be refused.
    int occ = 0;
    if (hipOccupancyMaxActiveBlocksPerMultiprocessor(&occ, (const void*)k_fused,
                                                     256, 0) != hipSuccess || occ < 1)
        occ = 1;
    long long nb_ll = (long long)occ * 256;    // 256 CUs on MI355X
    if (nb_ll > 2048) nb_ll = 2048;
    int NB = (int)(nb_ll & ~7LL);              // multiple of 8 for slice striding
    if (NB < 256) NB = 256;
    // phase A1 requires nb*256 >= N
    while ((long long)NB * 256 < N) NB += 8;   // unreachable for this problem size

    void* args[] = {
        (void*)&xw, (void*)&a_src, (void*)&a_dst, (void*)&ei, (void*)&E, (void*)&N,
        (void*)&deg, (void*)&row_ptr, (void*)&cursor, (void*)&partial,
        (void*)&pk, (void*)&xw2, (void*)&b1, (void*)&W2,
        (void*)&att_src2, (void*)&att_dst2, (void*)&b2, (void*)&out
    };
    hipLaunchCooperativeKernel((const void*)k_fused, dim3(NB), dim3(256),
                               args, 0, stream);
}

// Round 10
// 466.031 us; speedup vs baseline: 2.2117x; 2.2117x over previous
//
#include <hip/hip_runtime.h>
#include <hip/hip_bf16.h>
#include <cstdint>
#include <cstddef>
#include <math.h>

#define NEG_SLOPE 0.2f

__device__ __forceinline__ float lrelu(float x) { return x > 0.f ? x : NEG_SLOPE * x; }

// Layouts (r6-proven):
//  xw  slice-major [8][N][16]: k_agg pins slice->XCD (blockIdx%8); per-XCD gather
//      working set 3.2 MB < 4 MB L2 (FETCH 320->70 MB, r4).
//  pk  head-major planes [4][Et] packed {src:int, e:float}: one broadcast dwordx2
//      per edge in k_agg. e precomputed in scatter (r7 proved on-the-fly recompute
//      costs more than it saves).
//  r10 k_agg: 4 lanes/dst x 16 dsts/wave - 16 independent chains/wave, no csum
//      reduce, 2-shuffle epilogue (r6 had 5x4-shuffle cascade + 4 slots/dst).
//  Cooperative single-kernel fusion DISPROVEN (r9: grid.sync L2-drain -> 268 MB
//  writes, 1343 us). Multi-kernel + warm L2 wins.

// ================= K1: GEMM (blocks < GB) UNION degree-count (blocks >= GB) ======
__global__ __launch_bounds__(256) void k_gemm_count(
    const float* __restrict__ x, const float* __restrict__ W1,
    const float* __restrict__ att_src, const float* __restrict__ att_dst,
    const int* __restrict__ ei, int E, int N, int GB,
    float* __restrict__ xw, float* __restrict__ a_src, float* __restrict__ a_dst,
    int* __restrict__ deg)
{
    __shared__ float As[32 * 68];
    __shared__ float Bs[32 * 132];

    if (blockIdx.x >= GB) {                    // ---- count blocks (overlap with GEMM)
        const int Et = E + N;
        const int stride = (gridDim.x - GB) * 256;
        for (int e = (blockIdx.x - GB) * 256 + threadIdx.x; e < Et; e += stride) {
            int d = (e < E) ? ei[(size_t)E + e] : (e - E);
            atomicAdd(&deg[d], 1);
        }
        return;
    }

    const int tid = threadIdx.x;
    const int tx = tid & 31, ty = tid >> 5;
    const int bm = blockIdx.x * 64;
    float acc[8][4] = {};

    for (int k0 = 0; k0 < 128; k0 += 32) {
        #pragma unroll
        for (int t = tid; t < 512; t += 256) {
            int r = t >> 3, q = t & 7;
            int n = bm + r;
            float4 f = make_float4(0.f, 0.f, 0.f, 0.f);
            if (n < N) f = *(const float4*)(x + (size_t)n * 128 + k0 + 4 * q);
            As[(4*q+0)*68 + r] = f.x; As[(4*q+1)*68 + r] = f.y;
            As[(4*q+2)*68 + r] = f.z; As[(4*q+3)*68 + r] = f.w;
        }
        #pragma unroll
        for (int t = tid; t < 1024; t += 256) {
            int c = t >> 3, q = t & 7;
            float4 f = *(const float4*)(W1 + (size_t)c * 128 + k0 + 4 * q);
            Bs[(4*q+0)*132 + c] = f.x; Bs[(4*q+1)*132 + c] = f.y;
            Bs[(4*q+2)*132 + c] = f.z; Bs[(4*q+3)*132 + c] = f.w;
        }
        __syncthreads();
        #pragma unroll 8
        for (int kk = 0; kk < 32; kk++) {
            float4 a0 = *(const float4*)&As[kk * 68 + ty * 8];
            float4 a1 = *(const float4*)&As[kk * 68 + ty * 8 + 4];
            float4 b4 = *(const float4*)&Bs[kk * 132 + tx * 4];
            float a[8] = {a0.x, a0.y, a0.z, a0.w, a1.x, a1.y, a1.z, a1.w};
            float b[4] = {b4.x, b4.y, b4.z, b4.w};
            #pragma unroll
            for (int i = 0; i < 8; i++)
                #pragma unroll
                for (int j = 0; j < 4; j++) acc[i][j] = fmaf(a[i], b[j], acc[i][j]);
        }
        __syncthreads();
    }

    float asv[4], adv[4];
    #pragma unroll
    for (int j = 0; j < 4; j++) { asv[j] = att_src[tx*4+j]; adv[j] = att_dst[tx*4+j]; }
    const int slice = tx >> 2, cio = (tx & 3) * 4, head = tx >> 3;

    #pragma unroll
    for (int i = 0; i < 8; i++) {
        int n = bm + ty * 8 + i;
        float sv = 0.f, dv = 0.f;
        #pragma unroll
        for (int j = 0; j < 4; j++) {
            sv = fmaf(acc[i][j], asv[j], sv);
            dv = fmaf(acc[i][j], adv[j], dv);
        }
        #pragma unroll
        for (int off = 1; off < 8; off <<= 1) {   // 8 lanes of one head
            sv += __shfl_xor(sv, off);
            dv += __shfl_xor(dv, off);
        }
        if (n < N) {
            *(float4*)&xw[((size_t)slice * N + n) * 16 + cio] =
                make_float4(acc[i][0], acc[i][1], acc[i][2], acc[i][3]);
            if ((tx & 7) == 0) {
                a_src[n * 4 + head] = sv;
                a_dst[n * 4 + head] = dv;
            }
        }
    }
}

// ================= K2: single-pass decoupled-lookback scan; zeroes xw2 ===========
// 25 blocks (2048 elems each) — trivially co-resident, so the lookback spin is safe.
// post[b] encodes (value<<2)|status: 0 = not ready, 1 = aggregate, 2 = inclusive.
__global__ __launch_bounds__(256) void k_scan_lb(const int* __restrict__ deg,
                                                 int* __restrict__ row_ptr,
                                                 int* __restrict__ cursor,
                                                 float* __restrict__ xw2,
                                                 unsigned* __restrict__ post,
                                                 int N, int nblk)
{
    __shared__ int sw[4];
    __shared__ int s_excl;
    const int b = blockIdx.x, tid = threadIdx.x, wv = tid >> 6, lane = tid & 63;
    const int base = b * 2048 + tid * 8;

    int v[8];
    #pragma unroll
    for (int i = 0; i < 8; i++) v[i] = (base + i < N) ? deg[base + i] : 0;
    int tsum = 0;
    #pragma unroll
    for (int i = 0; i < 8; i++) tsum += v[i];

    int inc = tsum;
    #pragma unroll
    for (int off = 1; off < 64; off <<= 1) {
        int u = __shfl_up(inc, off);
        if (lane >= off) inc += u;
    }
    if (lane == 63) sw[wv] = inc;
    __syncthreads();
    int woff = 0;
    for (int i = 0; i < wv; i++) woff += sw[i];
    const int thr_excl = woff + inc - tsum;
    const int total = sw[0] + sw[1] + sw[2] + sw[3];

    if (tid == 0) {
        int excl = 0;
        if (b == 0) {
            __hip_atomic_store(&post[0], ((unsigned)total << 2) | 2u,
                               __ATOMIC_RELEASE, __HIP_MEMORY_SCOPE_AGENT);
        } else {
            __hip_atomic_store(&post[b], ((unsigned)total << 2) | 1u,
                               __ATOMIC_RELEASE, __HIP_MEMORY_SCOPE_AGENT);
            int j = b - 1;
            long long sum = 0;
            while (true) {
                unsigned pv = __hip_atomic_load(&post[j], __ATOMIC_ACQUIRE,
                                                __HIP_MEMORY_SCOPE_AGENT);
                unsigned st = pv & 3u;
                if (st == 0u) { __builtin_amdgcn_s_sleep(1); continue; }
                sum += (pv >> 2);
                if (st == 2u) break;
                j--;
            }
            excl = (int)sum;
            __hip_atomic_store(&post[b], ((unsigned)(excl + total) << 2) | 2u,
                               __ATOMIC_RELEASE, __HIP_MEMORY_SCOPE_AGENT);
        }
        s_excl = excl;
        if (b == nblk - 1) row_ptr[N] = excl + total;
    }
    __syncthreads();

    int run = s_excl + thr_excl;
    #pragma unroll
    for (int i = 0; i < 8; i++) {
        int idx = base + i;
        if (idx < N) {
            row_ptr[idx] = run;
            cursor[idx]  = run;
            xw2[idx]     = 0.f;
            run += v[i];
        }
    }
}

// ================= K3: scatter + packed unnormalized softmax weights ==============
__global__ void k_scatter(const int* __restrict__ ei, int E, int N,
                          int* __restrict__ cursor,
                          const float* __restrict__ a_src,
                          const float* __restrict__ a_dst,
                          uint2* __restrict__ pk, int Et)
{
    int e = blockIdx.x * blockDim.x + threadIdx.x;
    if (e >= Et) return;
    int s, d;
    if (e < E) { s = ei[e]; d = ei[(size_t)E + e]; }
    else       { s = d = e - E; }
    int pos = atomicAdd(&cursor[d], 1);
    float4 as4 = ((const float4*)a_src)[s];
    float4 ad4 = ((const float4*)a_dst)[d];
    unsigned us = (unsigned)s;
    pk[(size_t)0 * Et + pos] = make_uint2(us, __float_as_uint(__expf(lrelu(as4.x + ad4.x))));
    pk[(size_t)1 * Et + pos] = make_uint2(us, __float_as_uint(__expf(lrelu(as4.y + ad4.y))));
    pk[(size_t)2 * Et + pos] = make_uint2(us, __float_as_uint(__expf(lrelu(as4.z + ad4.z))));
    pk[(size_t)3 * Et + pos] = make_uint2(us, __float_as_uint(__expf(lrelu(as4.w + ad4.w))));
}

// ================= K4: agg — 4 lanes/dst x 16 dsts/wave, slice->XCD pinned ========
// Per edge: one broadcast dwordx2 (pk) + one 64B-line float4 gather. csum needs no
// reduce (every lane sees every edge); epilogue is 2 shuffles + 1 atomic per dst.
__global__ __launch_bounds__(256) void k_agg(const float* __restrict__ xw,
                                             const uint2* __restrict__ pk,
                                             const int* __restrict__ row_ptr,
                                             const float* __restrict__ b1,
                                             const float* __restrict__ W2,
                                             float* __restrict__ xw2, int N, int Et)
{
    const int slice = blockIdx.x & 7;
    const int dbase = (blockIdx.x >> 3) * 64;
    const int wv = threadIdx.x >> 6, lane = threadIdx.x & 63;
    const int grp = lane >> 2, li = lane & 3;     // 16 dst-groups x 4 ch-lanes
    const int d = dbase + wv * 16 + grp;
    if (d >= N) return;
    const float4* xs4 = (const float4*)(xw + (size_t)slice * N * 16);
    const uint2*  ph  = pk + (size_t)(slice >> 1) * Et;

    const int beg = row_ptr[d], end = row_ptr[d + 1];
    float4 acc = make_float4(0.f, 0.f, 0.f, 0.f);
    float csum = 0.f;
    for (int k = beg; k < end; ++k) {
        uint2 p = ph[k];
        float c = __uint_as_float(p.y);
        float4 v = xs4[(size_t)p.x * 4 + li];
        acc.x = fmaf(c, v.x, acc.x);
        acc.y = fmaf(c, v.y, acc.y);
        acc.z = fmaf(c, v.z, acc.z);
        acc.w = fmaf(c, v.w, acc.w);
        csum += c;
    }
    float4 bb = ((const float4*)b1)[slice * 4 + li];
    float4 ww = ((const float4*)W2)[slice * 4 + li];
    float inv = 1.f / (csum + 1e-16f);
    float t = fmaxf(fmaf(acc.x, inv, bb.x), 0.f) * ww.x
            + fmaxf(fmaf(acc.y, inv, bb.y), 0.f) * ww.y
            + fmaxf(fmaf(acc.z, inv, bb.z), 0.f) * ww.z
            + fmaxf(fmaf(acc.w, inv, bb.w), 0.f) * ww.w;
    t += __shfl_xor(t, 1);
    t += __shfl_xor(t, 2);
    if (li == 0) atomicAdd(&xw2[d], t);
}

// ================= K5: layer 2 — scalar GAT head, 4 dsts/wave x 16 lanes ==========
__global__ __launch_bounds__(256) void k_layer2(const float* __restrict__ xw2,
                                                const int* __restrict__ row_ptr,
                                                const uint2* __restrict__ pk0,
                                                const float* __restrict__ att_src2,
                                                const float* __restrict__ att_dst2,
                                                const float* __restrict__ b2,
                                                float* __restrict__ out, int N)
{
    int grpi = (blockIdx.x * blockDim.x + threadIdx.x) >> 6;
    int lane = threadIdx.x & 63;
    int sub  = lane >> 4, li = lane & 15;
    int d    = grpi * 4 + sub;
    if (d >= N) return;
    float as2  = att_src2[0];
    float adst = xw2[d] * att_dst2[0];
    float l = 0.f, acc = 0.f;
    int beg = row_ptr[d], end = row_ptr[d + 1];
    for (int j = beg + li; j < end; j += 16) {
        int s = (int)pk0[j].x;
        float xs = xw2[s];
        float p = __expf(lrelu(fmaf(xs, as2, adst)));
        l += p;
        acc = fmaf(p, xs, acc);
    }
    #pragma unroll
    for (int off = 1; off < 16; off <<= 1) {
        l   += __shfl_xor(l, off);
        acc += __shfl_xor(acc, off);
    }
    if (li == 0) out[d] = acc / (l + 1e-16f) + b2[0];
}

extern "C" void kernel_launch(void* const* d_in, const int* in_sizes, int n_in,
                              void* d_out, int out_size, void* d_ws, size_t ws_size,
                              hipStream_t stream)
{
    const float* x        = (const float*)d_in[0];
    const int*   ei       = (const int*)d_in[1];
    const float* W1       = (const float*)d_in[2];
    const float* att_src1 = (const float*)d_in[3];
    const float* att_dst1 = (const float*)d_in[4];
    const float* b1       = (const float*)d_in[5];
    const float* W2       = (const float*)d_in[6];
    const float* att_src2 = (const float*)d_in[7];
    const float* att_dst2 = (const float*)d_in[8];
    const float* b2       = (const float*)d_in[9];
    float* out = (float*)d_out;

    const int N  = in_sizes[0] / 128;
    const int E  = in_sizes[1] / 2;
    const int Et = E + N;
    const int nblk = (N + 2047) / 2048;        // lookback-scan blocks (25 for N=50k)

    char* p = (char*)d_ws;
    auto alloc = [&](size_t bytes) {
        char* r = p;
        p += (bytes + 255) & ~(size_t)255;
        return (void*)r;
    };
    float*    xw      = (float*)alloc((size_t)N * 128 * 4);  // slice-major [8][N][16]
    float*    a_src   = (float*)alloc((size_t)N * 4 * 4);
    float*    a_dst   = (float*)alloc((size_t)N * 4 * 4);
    float*    xw2     = (float*)alloc((size_t)N * 4);
    int*      degpost = (int*)alloc((size_t)(N + nblk + 8) * 4); // deg + post: 1 memset
    int*      deg     = degpost;
    unsigned* post    = (unsigned*)(degpost + N);
    int*      row_ptr = (int*)alloc((size_t)(N + 1) * 4);
    int*      cursor  = (int*)alloc((size_t)N * 4);
    uint2*    pk      = (uint2*)alloc((size_t)4 * Et * 8);   // [4][Et] packed {s, e_h}

    hipMemsetAsync(degpost, 0, (size_t)(N + nblk + 8) * 4, stream);

    const int GB = (N + 63) / 64;
    k_gemm_count<<<GB + 256, 256, 0, stream>>>(x, W1, att_src1, att_dst1, ei, E, N, GB,
                                               xw, a_src, a_dst, deg);
    k_scan_lb  <<<nblk,            256, 0, stream>>>(deg, row_ptr, cursor, xw2, post,
                                                     N, nblk);
    k_scatter  <<<(Et + 255)/256,  256, 0, stream>>>(ei, E, N, cursor, a_src, a_dst,
                                                     pk, Et);
    k_agg      <<<((N + 63)/64)*8, 256, 0, stream>>>(xw, pk, row_ptr, b1, W2, xw2,
                                                     N, Et);
    k_layer2   <<<(N + 15)/16,     256, 0, stream>>>(xw2, row_ptr, pk, att_src2,
                                                     att_dst2, b2, out, N);
}